// Round 5
// baseline (211.004 us; speedup 1.0000x reference)
//
#include <hip/hip_runtime.h>
#include <hip/hip_bf16.h>

#define BB 8
#define LL 4096
#define NCH 8192
#define IDIM 256
#define KDIM 512
#define ODIM 512
#define NDIR 6
#define TOT (BB * LL)  // 32768

// Per-dir bucket capacity (expected ~5461 per dir, 8192 = huge headroom).
#define CAP 8192
#define IDX_OFF 64
#define ROWS_OFF (64 + 8 * CAP)
#define WS_W_OFF (64 + 16 * CAP)
#define W_ELEMS (NDIR * ODIM * KDIM)  // 1,572,864
#define N_W8 (W_ELEMS / 8)            // 196,608 -> 768 blocks

#define MTILES (TOT / 128 + NDIR)  // 262 blocks, full-N tiles

typedef short short8 __attribute__((ext_vector_type(8)));
typedef float floatx4 __attribute__((ext_vector_type(4)));

__device__ inline void async_copy16(const void* g, void* l) {
  __builtin_amdgcn_global_load_lds(
      (const __attribute__((address_space(1))) void*)g,
      (__attribute__((address_space(3))) void*)l, 16, 0, 0);
}

__device__ inline void cvt8(const float* __restrict__ src,
                            __hip_bfloat16* __restrict__ dst, int i) {
  const floatx4* s = (const floatx4*)src;
  floatx4 a = s[2 * i];
  floatx4 b = s[2 * i + 1];
  union { short8 v; __hip_bfloat16 h[8]; } u;
  u.h[0] = __float2bfloat16(a[0]); u.h[1] = __float2bfloat16(a[1]);
  u.h[2] = __float2bfloat16(a[2]); u.h[3] = __float2bfloat16(a[3]);
  u.h[4] = __float2bfloat16(b[0]); u.h[5] = __float2bfloat16(b[1]);
  u.h[6] = __float2bfloat16(b[2]); u.h[7] = __float2bfloat16(b[3]);
  ((short8*)dst)[i] = u.v;
}

// ---- prep: cvt(W) + scatter into fixed-cap buckets (fused, 896 blocks) ----
__global__ __launch_bounds__(256) void prep_kernel(
    const float* __restrict__ W, const int* __restrict__ vec,
    const int* __restrict__ child_l, const int* __restrict__ child_r,
    const int* __restrict__ drev, const int* __restrict__ dmap,
    int* __restrict__ ws) {
  __hip_bfloat16* W_bf = (__hip_bfloat16*)(ws + WS_W_OFF);
  int gid = blockIdx.x * 256 + threadIdx.x;
  if (gid < N_W8) {
    cvt8(W, W_bf, gid);
  } else {
    __shared__ int lcnt[8];
    __shared__ int gbase[8];
    int tid = threadIdx.x;
    if (tid < 8) lcnt[tid] = 0;
    __syncthreads();
    int lin = gid - N_W8;
    int l = lin & (LL - 1);
    int v = vec[lin];
    int dir = dmap[v] & 7;
    int sw = drev[v];
    int cl = child_l[l];
    int cr = child_r[l];
    int r0 = sw ? cr : cl;
    int r1 = sw ? cl : cr;
    int pos = atomicAdd(&lcnt[dir], 1);
    __syncthreads();
    if (tid < 8) gbase[tid] = lcnt[tid] ? atomicAdd(&ws[tid], lcnt[tid]) : 0;
    __syncthreads();
    int slot = dir * CAP + gbase[dir] + pos;
    ws[IDX_OFF + slot] = lin;
    ws[ROWS_OFF + slot] = r0 | (r1 << 16);
  }
}

// ---- grouped GEMM: 128 rows x FULL N=512 per block, 8 waves (2m x 4n) ----
// A staged as f32 DIRECTLY from `last` (no pre-cvt pass) into 2x32KB LDS,
// in-register cvt to bf16. Global-side XOR swizzle (16B unit ^= row&15)
// makes ds_read conflict-free while global_load_lds dest stays linear.
// 2-barrier counted-vmcnt pipeline: vmcnt(4) leaves next stage in flight.
// A gathered ONCE per m-tile (no n-split redundancy); B from L2-hot W_bf.
__global__ __launch_bounds__(512) void gemm_kernel(
    const float* __restrict__ last, const float* __restrict__ bias,
    const float* __restrict__ alpha_m, const int* __restrict__ ws,
    float* __restrict__ out) {
  __shared__ float Als[2][128 * 64];  // 2 x 32 KB

  const int mt = blockIdx.x;
  // ---- tile -> dir mapping (counts = fill cursors at ws[0..7]) ----
  int d = -1, count = 0, m_base = 0;
  {
    int tb = 0;
    for (int dd = 0; dd < 8; ++dd) {
      int c = ws[dd];
      int ntile = (c + 127) >> 7;
      if (mt < tb + ntile) { d = dd; count = c; m_base = (mt - tb) * 128; break; }
      tb += ntile;
    }
  }
  if (d < 0) return;

  const int* idxA = ws + IDX_OFF + d * CAP;
  const int* rowsA = ws + ROWS_OFF + d * CAP;
  const char* W_bf = (const char*)(ws + WS_W_OFF);
  const char* lastc = (const char*)last;

  const int tid = threadIdx.x;
  const int wave = __builtin_amdgcn_readfirstlane(tid >> 6);
  const int lane = tid & 63;
  const int lane15 = lane & 15;
  const int quad = lane >> 4;
  const int wm = wave >> 2;  // 0..1 : 64-row half
  const int wn = wave & 3;   // 0..3 : 128-col strip

  // ---- A staging descriptors: wave covers rows 16w..16w+15, 4 instrs x 4 rows
  // source 16B-unit = (lane&15) ^ (row&15)  [swizzle]; LDS stays linear.
  int asrc0[4], asrc1[4];  // byte offsets into last (row base + swz unit)
  int ldsoff[4];           // f32 index of instr base in Als
#pragma unroll
  for (int g = 0; g < 4; ++g) {
    int r = wave * 16 + g * 4 + (lane >> 4);  // local row 0..127
    ldsoff[g] = (wave * 16 + g * 4) * 64;
    int gr = m_base + r;
    if (gr >= count) gr = count - 1;  // clamp (tile exists => count>0)
    int lin = idxA[gr] & (TOT - 1);
    int rr = rowsA[gr];
    int b = lin >> 12;
    int off = (((lane & 15) ^ (r & 15)) * 16);  // swizzled byte off in 256B chunk
    asrc0[g] = (b * NCH + (rr & (NCH - 1))) * 1024 + off;
    asrc1[g] = (b * NCH + ((rr >> 16) & (NCH - 1))) * 1024 + off;
  }
  // ---- B fragment byte offsets (bf16 W copy, L2-hot 3 MB) ----
  int boff[8];
#pragma unroll
  for (int j = 0; j < 8; ++j)
    boff[j] = ((d * ODIM + wn * 128 + j * 16 + lane15) * KDIM + quad * 8) * 2;

  floatx4 acc[4][8] = {};

  // prologue: stage t=0 into buf 0
#pragma unroll
  for (int g = 0; g < 4; ++g)
    async_copy16(lastc + asrc0[g], &Als[0][ldsoff[g]]);

#pragma unroll
  for (int t = 0; t < 8; ++t) {
    const int cur = t & 1;
    // B loads FIRST (so vmcnt(4) waits them), then next stage (stays in flight)
    short8 bfr[2][8];
#pragma unroll
    for (int s = 0; s < 2; ++s)
#pragma unroll
      for (int j = 0; j < 8; ++j)
        bfr[s][j] = *(const short8*)(W_bf + boff[j] + (t * 64 + s * 32) * 2);
    if (t < 7) {
      const int tn = t + 1;
      const int ko = (tn & 3) * 256;  // 64 f32 per k-step within the 1KB row
#pragma unroll
      for (int g = 0; g < 4; ++g)
        async_copy16(lastc + (tn < 4 ? asrc0[g] : asrc1[g]) + ko,
                     &Als[cur ^ 1][ldsoff[g]]);
      asm volatile("s_waitcnt vmcnt(4)" ::: "memory");  // cur stage + B done
    } else {
      asm volatile("s_waitcnt vmcnt(0)" ::: "memory");
    }
    __builtin_amdgcn_sched_barrier(0);
    __builtin_amdgcn_s_barrier();  // all waves' cur-stage visible

#pragma unroll
    for (int s = 0; s < 2; ++s) {
#pragma unroll
      for (int i = 0; i < 4; ++i) {
        const int r = wm * 64 + i * 16 + lane15;
        const int ulo = (2 * (quad + 4 * s)) ^ lane15;  // swizzled 16B unit
        const floatx4 lo = *(const floatx4*)&Als[cur][r * 64 + ulo * 4];
        const floatx4 hi = *(const floatx4*)&Als[cur][r * 64 + (ulo ^ 1) * 4];
        union { short8 v; __hip_bfloat16 h[8]; } u;
        u.h[0] = __float2bfloat16(lo[0]); u.h[1] = __float2bfloat16(lo[1]);
        u.h[2] = __float2bfloat16(lo[2]); u.h[3] = __float2bfloat16(lo[3]);
        u.h[4] = __float2bfloat16(hi[0]); u.h[5] = __float2bfloat16(hi[1]);
        u.h[6] = __float2bfloat16(hi[2]); u.h[7] = __float2bfloat16(hi[3]);
#pragma unroll
        for (int j = 0; j < 8; ++j)
          acc[i][j] = __builtin_amdgcn_mfma_f32_16x16x32_bf16(u.v, bfr[s][j], acc[i][j], 0, 0, 0);
      }
    }
    __builtin_amdgcn_s_barrier();  // all reads done before re-stage of this buf
  }

  // ---- epilogue: bias + leaky relu, scatter rows ----
  const float alpha = alpha_m[d];
  float bj[8];
#pragma unroll
  for (int j = 0; j < 8; ++j)
    bj[j] = bias[d * ODIM + wn * 128 + j * 16 + lane15];

#pragma unroll
  for (int i = 0; i < 4; ++i) {
#pragma unroll
    for (int reg = 0; reg < 4; ++reg) {
      int row_id = m_base + wm * 64 + i * 16 + quad * 4 + reg;
      if (row_id >= count) continue;
      int lin = idxA[row_id] & (TOT - 1);
      float* orow = out + (long long)lin * ODIM + wn * 128;
#pragma unroll
      for (int j = 0; j < 8; ++j) {
        float y = acc[i][j][reg] + bj[j];
        y = y > 0.f ? y : alpha * y;
        orow[j * 16 + lane15] = y;
      }
    }
  }
}

extern "C" void kernel_launch(void* const* d_in, const int* in_sizes, int n_in,
                              void* d_out, int out_size, void* d_ws, size_t ws_size,
                              hipStream_t stream) {
  const float* last = (const float*)d_in[0];
  const float* W = (const float*)d_in[1];
  const float* bias = (const float*)d_in[2];
  const float* alpha = (const float*)d_in[3];
  const int* child_l = (const int*)d_in[4];
  const int* child_r = (const int*)d_in[5];
  const int* vec = (const int*)d_in[6];
  const int* drev = (const int*)d_in[7];
  const int* dmap = (const int*)d_in[8];

  int* ws = (int*)d_ws;

  hipMemsetAsync(ws, 0, 64 * sizeof(int), stream);
  // prep: W-cvt (768 blocks) + scatter (128 blocks)
  prep_kernel<<<(N_W8 / 256) + (TOT / 256), 256, 0, stream>>>(
      W, vec, child_l, child_r, drev, dmap, ws);
  gemm_kernel<<<MTILES, 512, 0, stream>>>(last, bias, alpha, ws, (float*)d_out);
}

// Round 6
// 164.020 us; speedup vs baseline: 1.2865x; 1.2865x over previous
//
#include <hip/hip_runtime.h>
#include <hip/hip_bf16.h>

#define BB 8
#define LL 4096
#define NCH 8192
#define IDIM 256
#define KDIM 512
#define ODIM 512
#define NDIR 6
#define TOT (BB * LL)  // 32768

// Per-dir fixed-capacity buckets (expected ~5461/dir; 8192 = huge headroom).
#define CAP 8192
#define IDX_OFF 64
#define ROWS_OFF (64 + 8 * CAP)
#define WS_LAST_OFF (64 + 16 * CAP)
#define LAST_ELEMS (BB * NCH * IDIM)  // 16,777,216
#define W_ELEMS (NDIR * ODIM * KDIM)  // 1,572,864
#define N_LAST8 (LAST_ELEMS / 8)      // 2,097,152 -> 8192 blocks
#define N_W8 (W_ELEMS / 8)            // 196,608  -> 768 blocks

// gemm grid: 4 n-tiles x 262 m-tiles = 1048 = 8 * 131 (bijective XCD swizzle)
#define GEMM_CHUNK 131

typedef short short8 __attribute__((ext_vector_type(8)));
typedef float floatx4 __attribute__((ext_vector_type(4)));

__device__ inline void async_copy16(const void* g, void* l) {
  __builtin_amdgcn_global_load_lds(
      (const __attribute__((address_space(1))) void*)g,
      (__attribute__((address_space(3))) void*)l, 16, 0, 0);
}

__device__ inline void cvt8(const float* __restrict__ src,
                            __hip_bfloat16* __restrict__ dst, int i) {
  const floatx4* s = (const floatx4*)src;
  floatx4 a = s[2 * i];
  floatx4 b = s[2 * i + 1];
  union { short8 v; __hip_bfloat16 h[8]; } u;
  u.h[0] = __float2bfloat16(a[0]); u.h[1] = __float2bfloat16(a[1]);
  u.h[2] = __float2bfloat16(a[2]); u.h[3] = __float2bfloat16(a[3]);
  u.h[4] = __float2bfloat16(b[0]); u.h[5] = __float2bfloat16(b[1]);
  u.h[6] = __float2bfloat16(b[2]); u.h[7] = __float2bfloat16(b[3]);
  ((short8*)dst)[i] = u.v;
}

// ---- prep: cvt(last) + cvt(W) + scatter into fixed-cap buckets, fused ----
__global__ __launch_bounds__(256) void prep_kernel(
    const float* __restrict__ last, const float* __restrict__ W,
    const int* __restrict__ vec, const int* __restrict__ child_l,
    const int* __restrict__ child_r, const int* __restrict__ drev,
    const int* __restrict__ dmap, int* __restrict__ ws) {
  __hip_bfloat16* last_bf = (__hip_bfloat16*)(ws + WS_LAST_OFF);
  __hip_bfloat16* W_bf = last_bf + LAST_ELEMS;
  int gid = blockIdx.x * 256 + threadIdx.x;
  if (gid < N_LAST8) {
    cvt8(last, last_bf, gid);
  } else if (gid < N_LAST8 + N_W8) {
    cvt8(W, W_bf, gid - N_LAST8);
  } else {
    __shared__ int lcnt[8];
    __shared__ int gbase[8];
    int tid = threadIdx.x;
    if (tid < 8) lcnt[tid] = 0;
    __syncthreads();
    int lin = gid - (N_LAST8 + N_W8);
    int l = lin & (LL - 1);
    int v = vec[lin];
    int dir = dmap[v] & 7;
    int sw = drev[v];
    int cl = child_l[l];
    int cr = child_r[l];
    int r0 = sw ? cr : cl;
    int r1 = sw ? cl : cr;
    int pos = atomicAdd(&lcnt[dir], 1);
    __syncthreads();
    if (tid < 8) gbase[tid] = lcnt[tid] ? atomicAdd(&ws[tid], lcnt[tid]) : 0;
    __syncthreads();
    int slot = dir * CAP + gbase[dir] + pos;
    ws[IDX_OFF + slot] = lin;
    ws[ROWS_OFF + slot] = r0 | (r1 << 16);
  }
}

// ---- grouped GEMM: 128x128 tile, BK=64, DEEP-PIPELINED LDS staging ----
// 4 waves (2x2), each wave 64x64 via 4x4 mfma_f32_16x16x32_bf16.
// A: 3 LDS buffers, staged 2 chunks ahead (covers HBM gather latency).
// B: 2 LDS buffers, staged 1 chunk ahead (L2-hot 3MB W copy).
// Counted vmcnt(12) keeps 12 stage-ops in flight across barriers — the
// pipeline NEVER drains in the main loop (R0..R3 all drained every step).
// FIFO accounting (issue order B(c+1) then A(c+2)):
//   outstanding after issue at iter c: A(c),B(c),A(c+1),B(c+1),A(c+2) = 20
//   vmcnt(12) retires exactly A(c),B(c) -> compute(c) safe.
__global__ __launch_bounds__(256) void gemm_kernel(
    const float* __restrict__ bias, const float* __restrict__ alpha_m,
    const int* __restrict__ ws, float* __restrict__ out) {
  __shared__ __hip_bfloat16 Als[3][128 * 64];  // 48 KB
  __shared__ __hip_bfloat16 Bls[2][128 * 64];  // 32 KB

  // bijective XCD swizzle: neighboring m-tiles' 4 n-tiles share one XCD L2.
  int flat = blockIdx.y * 4 + blockIdx.x;  // dispatch order (x fastest)
  int swz = (flat & 7) * GEMM_CHUNK + (flat >> 3);
  const int mt = swz >> 2;
  const int nt = swz & 3;

  // ---- tile -> dir mapping (counts = fill cursors at ws[0..7]) ----
  int d = -1, count = 0, m_base = 0;
  {
    int tb = 0;
    for (int dd = 0; dd < 8; ++dd) {
      int c = ws[dd];
      int ntile = (c + 127) >> 7;
      if (mt < tb + ntile) { d = dd; count = c; m_base = (mt - tb) * 128; break; }
      tb += ntile;
    }
  }
  if (d < 0) return;

  const int* idxA = ws + IDX_OFF + d * CAP;
  const int* rowsA = ws + ROWS_OFF + d * CAP;
  const __hip_bfloat16* last_bf = (const __hip_bfloat16*)(ws + WS_LAST_OFF);
  const __hip_bfloat16* W_bf = last_bf + LAST_ELEMS;

  const int tid = threadIdx.x;
  const int wave = __builtin_amdgcn_readfirstlane(tid >> 6);
  const int lane = tid & 63;
  const int lane15 = lane & 15;
  const int quad = lane >> 4;
  const int wm = wave >> 1;
  const int wn = wave & 1;
  const int n_blk = nt * 128;

  // ---- staging descriptors: per wave 4 A-instrs + 4 B-instrs, 8 rows each --
  // 16B-unit XOR swizzle (unit ^= row&7) applied on the GLOBAL source side;
  // LDS destination stays lane-linear (global_load_lds requirement).
  const __hip_bfloat16* ap0[4];
  const __hip_bfloat16* ap1[4];
  const __hip_bfloat16* bp[4];
  int ldsrow[4];
#pragma unroll
  for (int i = 0; i < 4; ++i) {
    int sr = wave * 32 + i * 8 + (lane >> 3);  // local row 0..127
    ldsrow[i] = (wave * 32 + i * 8) * 64;      // lds elem offset (wave-uniform)
    int lr = m_base + sr;
    if (lr >= count) lr = count - 1;  // clamp (tile exists => count>0)
    int lin = idxA[lr] & (TOT - 1);
    int rr = rowsA[lr];
    int b = lin >> 12;
    int r0 = rr & (NCH - 1);
    int r1 = (rr >> 16) & (NCH - 1);
    int xu = ((lane & 7) ^ (sr & 7)) * 8;  // swizzled 16B-unit -> elems
    ap0[i] = last_bf + (long long)(b * NCH + r0) * IDIM + xu;
    ap1[i] = last_bf + (long long)(b * NCH + r1) * IDIM + xu;
    bp[i] = W_bf + (long long)(d * ODIM + n_blk + sr) * KDIM + xu;
  }

#define STAGE_A(c, buf)                                              \
  {                                                                  \
    const int ko = ((c) & 3) * 64;                                   \
    _Pragma("unroll") for (int i = 0; i < 4; ++i)                    \
        async_copy16(((c) < 4 ? ap0[i] : ap1[i]) + ko,               \
                     &Als[(buf)][ldsrow[i]]);                        \
  }
#define STAGE_B(c, buf)                                              \
  {                                                                  \
    _Pragma("unroll") for (int i = 0; i < 4; ++i)                    \
        async_copy16(bp[i] + (c) * 64, &Bls[(buf)][ldsrow[i]]);      \
  }

  floatx4 acc[4][4] = {};
  const int lx = lane15 & 7;  // frag-read swizzle key (row&7 == lane15&7)

  // prologue: B(0), A(0), A(1)  (oldest-first so vmcnt retires them first)
  STAGE_B(0, 0);
  STAGE_A(0, 0);
  STAGE_A(1, 1);

#pragma unroll
  for (int c = 0; c < 8; ++c) {
    // barrier 1: all waves done reading the buffers we're about to overwrite
    // (B(c+1) reuses Bls[(c-1)&1], A(c+2) reuses Als[(c-1)%3]).
    __builtin_amdgcn_s_barrier();
    if (c < 7) STAGE_B(c + 1, (c + 1) & 1);
    if (c < 6) STAGE_A(c + 2, (c + 2) % 3);
    if (c < 6) {
      asm volatile("s_waitcnt vmcnt(12)" ::: "memory");  // A(c),B(c) landed
    } else if (c == 6) {
      asm volatile("s_waitcnt vmcnt(8)" ::: "memory");   // A(6),B(6) landed
    } else {
      asm volatile("s_waitcnt vmcnt(0)" ::: "memory");   // everything landed
    }
    __builtin_amdgcn_sched_barrier(0);
    // barrier 2: every wave's stage(c) visible to all
    __builtin_amdgcn_s_barrier();

    const __hip_bfloat16* Ab = Als[c % 3];
    const __hip_bfloat16* Bb = Bls[c & 1];
#pragma unroll
    for (int s = 0; s < 2; ++s) {
      const int xcol = ((quad + 4 * s) ^ lx) * 8;  // swizzled elem offset
      short8 a[4], b[4];
#pragma unroll
      for (int i = 0; i < 4; ++i)
        a[i] = *(const short8*)&Ab[(wm * 64 + i * 16 + lane15) * 64 + xcol];
#pragma unroll
      for (int j = 0; j < 4; ++j)
        b[j] = *(const short8*)&Bb[(wn * 64 + j * 16 + lane15) * 64 + xcol];
#pragma unroll
      for (int i = 0; i < 4; ++i)
#pragma unroll
        for (int j = 0; j < 4; ++j)
          acc[i][j] = __builtin_amdgcn_mfma_f32_16x16x32_bf16(a[i], b[j], acc[i][j], 0, 0, 0);
    }
  }

  // ---- epilogue: bias + leaky relu, scatter rows ----
  const float alpha = alpha_m[d];
  float bj[4];
#pragma unroll
  for (int j = 0; j < 4; ++j)
    bj[j] = bias[d * ODIM + n_blk + wn * 64 + j * 16 + lane15];

#pragma unroll
  for (int i = 0; i < 4; ++i) {
#pragma unroll
    for (int reg = 0; reg < 4; ++reg) {
      int row_id = m_base + wm * 64 + i * 16 + quad * 4 + reg;
      if (row_id >= count) continue;
      int lin = idxA[row_id] & (TOT - 1);
      float* orow = out + (long long)lin * ODIM + n_blk + wn * 64;
#pragma unroll
      for (int j = 0; j < 4; ++j) {
        float y = acc[i][j][reg] + bj[j];
        y = y > 0.f ? y : alpha * y;
        orow[j * 16 + lane15] = y;
      }
    }
  }
}

extern "C" void kernel_launch(void* const* d_in, const int* in_sizes, int n_in,
                              void* d_out, int out_size, void* d_ws, size_t ws_size,
                              hipStream_t stream) {
  const float* last = (const float*)d_in[0];
  const float* W = (const float*)d_in[1];
  const float* bias = (const float*)d_in[2];
  const float* alpha = (const float*)d_in[3];
  const int* child_l = (const int*)d_in[4];
  const int* child_r = (const int*)d_in[5];
  const int* vec = (const int*)d_in[6];
  const int* drev = (const int*)d_in[7];
  const int* dmap = (const int*)d_in[8];

  int* ws = (int*)d_ws;

  hipMemsetAsync(ws, 0, 64 * sizeof(int), stream);
  // fused prep: last-cvt (8192 blocks) + W-cvt (768) + scatter (128)
  int prep_blocks = N_LAST8 / 256 + N_W8 / 256 + TOT / 256;
  prep_kernel<<<prep_blocks, 256, 0, stream>>>(last, W, vec, child_l, child_r,
                                               drev, dmap, ws);
  dim3 grid(ODIM / 128, TOT / 128 + NDIR, 1);  // 4 x 262 = 1048 blocks
  gemm_kernel<<<grid, 256, 0, stream>>>(bias, alpha, ws, (float*)d_out);
}

// Round 7
// 163.261 us; speedup vs baseline: 1.2924x; 1.0047x over previous
//
#include <hip/hip_runtime.h>
#include <hip/hip_bf16.h>

#define BB 8
#define LL 4096
#define NCH 8192
#define IDIM 256
#define KDIM 512
#define ODIM 512
#define NDIR 6
#define TOT (BB * LL)  // 32768

// Per-dir fixed-capacity buckets (expected ~5461/dir; 8192 = huge headroom).
#define CAP 8192
#define IDX_OFF 64
#define ROWS_OFF (64 + 8 * CAP)
#define WS_LAST_OFF (64 + 16 * CAP)
#define LAST_ELEMS (BB * NCH * IDIM)  // 16,777,216
#define W_ELEMS (NDIR * ODIM * KDIM)  // 1,572,864
#define N_LAST8 (LAST_ELEMS / 8)      // 2,097,152 -> 8192 blocks
#define N_W8 (W_ELEMS / 8)            // 196,608  -> 768 blocks

// gemm grid: 4 n-tiles x 262 m-tiles = 1048 = 8 * 131 (bijective XCD swizzle)
#define GEMM_CHUNK 131

typedef short short8 __attribute__((ext_vector_type(8)));
typedef float floatx4 __attribute__((ext_vector_type(4)));

__device__ inline void async_copy16(const void* g, void* l) {
  __builtin_amdgcn_global_load_lds(
      (const __attribute__((address_space(1))) void*)g,
      (__attribute__((address_space(3))) void*)l, 16, 0, 0);
}

__device__ inline void cvt8(const float* __restrict__ src,
                            __hip_bfloat16* __restrict__ dst, int i) {
  const floatx4* s = (const floatx4*)src;
  floatx4 a = s[2 * i];
  floatx4 b = s[2 * i + 1];
  union { short8 v; __hip_bfloat16 h[8]; } u;
  u.h[0] = __float2bfloat16(a[0]); u.h[1] = __float2bfloat16(a[1]);
  u.h[2] = __float2bfloat16(a[2]); u.h[3] = __float2bfloat16(a[3]);
  u.h[4] = __float2bfloat16(b[0]); u.h[5] = __float2bfloat16(b[1]);
  u.h[6] = __float2bfloat16(b[2]); u.h[7] = __float2bfloat16(b[3]);
  ((short8*)dst)[i] = u.v;
}

// ---- prep: cvt(last) + cvt(W) + scatter into fixed-cap buckets, fused ----
__global__ __launch_bounds__(256) void prep_kernel(
    const float* __restrict__ last, const float* __restrict__ W,
    const int* __restrict__ vec, const int* __restrict__ child_l,
    const int* __restrict__ child_r, const int* __restrict__ drev,
    const int* __restrict__ dmap, int* __restrict__ ws) {
  __hip_bfloat16* last_bf = (__hip_bfloat16*)(ws + WS_LAST_OFF);
  __hip_bfloat16* W_bf = last_bf + LAST_ELEMS;
  int gid = blockIdx.x * 256 + threadIdx.x;
  if (gid < N_LAST8) {
    cvt8(last, last_bf, gid);
  } else if (gid < N_LAST8 + N_W8) {
    cvt8(W, W_bf, gid - N_LAST8);
  } else {
    __shared__ int lcnt[8];
    __shared__ int gbase[8];
    int tid = threadIdx.x;
    if (tid < 8) lcnt[tid] = 0;
    __syncthreads();
    int lin = gid - (N_LAST8 + N_W8);
    int l = lin & (LL - 1);
    int v = vec[lin];
    int dir = dmap[v] & 7;
    int sw = drev[v];
    int cl = child_l[l];
    int cr = child_r[l];
    int r0 = sw ? cr : cl;
    int r1 = sw ? cl : cr;
    int pos = atomicAdd(&lcnt[dir], 1);
    __syncthreads();
    if (tid < 8) gbase[tid] = lcnt[tid] ? atomicAdd(&ws[tid], lcnt[tid]) : 0;
    __syncthreads();
    int slot = dir * CAP + gbase[dir] + pos;
    ws[IDX_OFF + slot] = lin;
    ws[ROWS_OFF + slot] = r0 | (r1 << 16);
  }
}

// ---- grouped GEMM: 128x128 tile, BK=32, deep pipeline, 4 blocks/CU ----
// 4 waves (2x2), each wave 64x64 via 4x4 mfma_f32_16x16x32_bf16, 16 K-steps.
// A: 3 x 8KB buffers (staged 2 ahead, covers gather latency).
// B: 2 x 8KB buffers (staged 1 ahead, L2-hot W copy).  Total LDS 40 KB ->
// 4 blocks/CU (16 waves/CU), grid 1048 ~= one fully-resident round.
// Counted vmcnt(6): pipeline never drains in the main loop.
// LDS layout: row-PAIRS packed into 128B lines; 16B-unit u' = parity*4+k16,
// stored at u = u' ^ (line&7)  (bank-conflict-free, 2-way max).
// Staging keeps lane-linear LDS dest; inverse permutation applied on the
// global source address (global_load_lds requirement).
__global__ __launch_bounds__(256, 4) void gemm_kernel(
    const float* __restrict__ bias, const float* __restrict__ alpha_m,
    const int* __restrict__ ws, float* __restrict__ out) {
  __shared__ __hip_bfloat16 Als[3][128 * 32];  // 24 KB
  __shared__ __hip_bfloat16 Bls[2][128 * 32];  // 16 KB

  // bijective XCD swizzle: neighboring m-tiles' 4 n-tiles share one XCD L2.
  int flat = blockIdx.y * 4 + blockIdx.x;  // dispatch order (x fastest)
  int swz = (flat & 7) * GEMM_CHUNK + (flat >> 3);
  const int mt = swz >> 2;
  const int nt = swz & 3;

  // ---- tile -> dir mapping (counts = fill cursors at ws[0..7]) ----
  int d = -1, count = 0, m_base = 0;
  {
    int tb = 0;
    for (int dd = 0; dd < 8; ++dd) {
      int c = ws[dd];
      int ntile = (c + 127) >> 7;
      if (mt < tb + ntile) { d = dd; count = c; m_base = (mt - tb) * 128; break; }
      tb += ntile;
    }
  }
  if (d < 0) return;

  const int* idxA = ws + IDX_OFF + d * CAP;
  const int* rowsA = ws + ROWS_OFF + d * CAP;
  const __hip_bfloat16* last_bf = (const __hip_bfloat16*)(ws + WS_LAST_OFF);
  const __hip_bfloat16* W_bf = last_bf + LAST_ELEMS;

  const int tid = threadIdx.x;
  const int wave = __builtin_amdgcn_readfirstlane(tid >> 6);
  const int lane = tid & 63;
  const int lane15 = lane & 15;
  const int quad = lane >> 4;
  const int wm = wave >> 1;
  const int wn = wave & 1;
  const int n_blk = nt * 128;

  // ---- staging descriptors: per wave 2 A-instrs + 2 B-instrs ----
  // instr I = wave*2+i covers rows [I*16, I*16+16) (two rows per 128B line).
  // lane l: line_local = l>>3, u' = (l&7)^(l>>3); row = I*16 + 2*(l>>3)+(u'>>2),
  // k16 = u'&3 (which 16B of the row's 64B k-chunk).
  const __hip_bfloat16* ap0[2];
  const __hip_bfloat16* ap1[2];
  const __hip_bfloat16* bp[2];
  int ldsoff[2];  // elem offset of instr base in buffer
  {
    const int lp = lane >> 3;
    const int up = (lane & 7) ^ lp;
    const int k16e = (up & 3) * 8;  // elem offset within 64B chunk
#pragma unroll
    for (int i = 0; i < 2; ++i) {
      const int I = wave * 2 + i;
      ldsoff[i] = I * 512;  // 1 KB per instr
      int row_local = I * 16 + 2 * lp + (up >> 2);
      int gr = m_base + row_local;
      if (gr >= count) gr = count - 1;  // clamp (tile exists => count>0)
      int lin = idxA[gr] & (TOT - 1);
      int rr = rowsA[gr];
      int b = lin >> 12;
      int r0 = rr & (NCH - 1);
      int r1 = (rr >> 16) & (NCH - 1);
      ap0[i] = last_bf + (long long)(b * NCH + r0) * IDIM + k16e;
      ap1[i] = last_bf + (long long)(b * NCH + r1) * IDIM + k16e;
      bp[i] = W_bf + (long long)(d * ODIM + n_blk + row_local) * KDIM + k16e;
    }
  }

#define STAGE_A(c, buf)                                               \
  {                                                                   \
    const int ko = ((c) & 7) * 32;                                    \
    _Pragma("unroll") for (int i = 0; i < 2; ++i)                     \
        async_copy16(((c) < 8 ? ap0[i] : ap1[i]) + ko,                \
                     &Als[(buf)][ldsoff[i]]);                         \
  }
#define STAGE_B(c, buf)                                               \
  {                                                                   \
    _Pragma("unroll") for (int i = 0; i < 2; ++i)                     \
        async_copy16(bp[i] + (c) * 32, &Bls[(buf)][ldsoff[i]]);       \
  }

  floatx4 acc[4][4] = {};
  // frag-read address pieces: row r -> line r>>1; u = (4*(r&1)+quad)^((r>>1)&7)
  const int t3 = lane15 >> 1;                      // (r>>1)&7 component
  const int col8 = (((lane15 & 1) * 4 + quad) ^ t3) * 8;  // swizzled elems

  // prologue: B(0), A(0), A(1)  (oldest-first for FIFO vmcnt retirement)
  STAGE_B(0, 0);
  STAGE_A(0, 0);
  STAGE_A(1, 1);

#pragma unroll
  for (int c = 0; c < 16; ++c) {
    // barrier 1: all waves done reading the buffers about to be overwritten
    __builtin_amdgcn_s_barrier();
    if (c < 15) STAGE_B(c + 1, (c + 1) & 1);
    if (c < 14) STAGE_A(c + 2, (c + 2) % 3);
    // FIFO: outstanding after issue = {A(c+1)2, B(c+1)2, A(c+2)2} = 6
    if (c < 14) {
      asm volatile("s_waitcnt vmcnt(6)" ::: "memory");   // A(c),B(c) landed
    } else if (c == 14) {
      asm volatile("s_waitcnt vmcnt(4)" ::: "memory");   // A(14),B(14) landed
    } else {
      asm volatile("s_waitcnt vmcnt(0)" ::: "memory");   // everything landed
    }
    __builtin_amdgcn_sched_barrier(0);
    // barrier 2: every wave's stage(c) visible to all
    __builtin_amdgcn_s_barrier();

    const __hip_bfloat16* Ab = Als[c % 3];
    const __hip_bfloat16* Bb = Bls[c & 1];
    short8 a[4], b[4];
#pragma unroll
    for (int i = 0; i < 4; ++i)
      a[i] = *(const short8*)&Ab[(wm * 32 + i * 8 + t3) * 64 + col8];
#pragma unroll
    for (int j = 0; j < 4; ++j)
      b[j] = *(const short8*)&Bb[(wn * 32 + j * 8 + t3) * 64 + col8];
#pragma unroll
    for (int i = 0; i < 4; ++i)
#pragma unroll
      for (int j = 0; j < 4; ++j)
        acc[i][j] = __builtin_amdgcn_mfma_f32_16x16x32_bf16(a[i], b[j], acc[i][j], 0, 0, 0);
  }

  // ---- epilogue: bias + leaky relu, scatter rows ----
  const float alpha = alpha_m[d];
  float bj[4];
#pragma unroll
  for (int j = 0; j < 4; ++j)
    bj[j] = bias[d * ODIM + n_blk + wn * 64 + j * 16 + lane15];

#pragma unroll
  for (int i = 0; i < 4; ++i) {
#pragma unroll
    for (int reg = 0; reg < 4; ++reg) {
      int row_id = m_base + wm * 64 + i * 16 + quad * 4 + reg;
      if (row_id >= count) continue;
      int lin = idxA[row_id] & (TOT - 1);
      float* orow = out + (long long)lin * ODIM + n_blk + wn * 64;
#pragma unroll
      for (int j = 0; j < 4; ++j) {
        float y = acc[i][j][reg] + bj[j];
        y = y > 0.f ? y : alpha * y;
        orow[j * 16 + lane15] = y;
      }
    }
  }
}

extern "C" void kernel_launch(void* const* d_in, const int* in_sizes, int n_in,
                              void* d_out, int out_size, void* d_ws, size_t ws_size,
                              hipStream_t stream) {
  const float* last = (const float*)d_in[0];
  const float* W = (const float*)d_in[1];
  const float* bias = (const float*)d_in[2];
  const float* alpha = (const float*)d_in[3];
  const int* child_l = (const int*)d_in[4];
  const int* child_r = (const int*)d_in[5];
  const int* vec = (const int*)d_in[6];
  const int* drev = (const int*)d_in[7];
  const int* dmap = (const int*)d_in[8];

  int* ws = (int*)d_ws;

  hipMemsetAsync(ws, 0, 64 * sizeof(int), stream);
  // fused prep: last-cvt (8192 blocks) + W-cvt (768) + scatter (128)
  int prep_blocks = N_LAST8 / 256 + N_W8 / 256 + TOT / 256;
  prep_kernel<<<prep_blocks, 256, 0, stream>>>(last, W, vec, child_l, child_r,
                                               drev, dmap, ws);
  dim3 grid(ODIM / 128, TOT / 128 + NDIR, 1);  // 4 x 262 = 1048 blocks
  gemm_kernel<<<grid, 256, 0, stream>>>(bias, alpha, ws, (float*)d_out);
}